// Round 19
// baseline (59.053 us; speedup 1.0000x reference)
//
#include <hip/hip_runtime.h>
#include <math.h>

#define NROWS 8192
#define DIM 512
#define INV_T 20.0f
#define QS 500.0f
// dequant * 1/T * log2(e), for exp2-based softmax accumulation
#define DEQ2 (INV_T * 1.4426950408889634f / (QS * QS))

typedef __attribute__((ext_vector_type(4))) int i32x4;

__device__ __forceinline__ void gload_lds16(const void* g, void* l) {
    __builtin_amdgcn_global_load_lds(
        (const __attribute__((address_space(1))) unsigned int*)g,
        (__attribute__((address_space(3))) unsigned int*)l, 16, 0, 0);
}

__device__ __forceinline__ void block_bar() {
    asm volatile("" ::: "memory");
    __builtin_amdgcn_s_barrier();
    asm volatile("" ::: "memory");
}

__device__ __forceinline__ float hw_exp2(float x) {
    float r;
    asm("v_exp_f32 %0, %1" : "=v"(r) : "v"(x));  // D = 2^S0, 1 inst
    return r;
}

__device__ __forceinline__ float dot4(float4 a, float4 b) {
    return a.x * b.x + a.y * b.y + a.z * b.z + a.w * b.w;
}

__device__ __forceinline__ int q4(float4 v, float s) {
    int b0 = __float2int_rn(fminf(fmaxf(v.x * s, -127.f), 127.f)) & 255;
    int b1 = __float2int_rn(fminf(fmaxf(v.y * s, -127.f), 127.f)) & 255;
    int b2 = __float2int_rn(fminf(fmaxf(v.z * s, -127.f), 127.f)) & 255;
    int b3 = __float2int_rn(fminf(fmaxf(v.w * s, -127.f), 127.f)) & 255;
    return b0 | (b1 << 8) | (b2 << 16) | (b3 << 24);
}

// One wave per row: L2-normalize, quantize to i8 (scale QS), exact fp32 diag,
// column log2-weights (0 or 1).
__global__ __launch_bounds__(256) void norm_kernel(
    const float* __restrict__ A, const float* __restrict__ S,
    const int* __restrict__ labels, signed char* __restrict__ aQ,
    signed char* __restrict__ sQ, float* __restrict__ diag,
    float* __restrict__ lw2) {
    const int wave = threadIdx.x >> 6, lane = threadIdx.x & 63;
    const int row = blockIdx.x * 4 + wave;
    const float4* a4 = (const float4*)(A + (size_t)row * DIM);
    const float4* s4 = (const float4*)(S + (size_t)row * DIM);
    float4 a0 = a4[lane], a1 = a4[lane + 64];
    float4 s0 = s4[lane], s1 = s4[lane + 64];
    float saa = dot4(a0, a0) + dot4(a1, a1);
    float sss = dot4(s0, s0) + dot4(s1, s1);
    float sas = dot4(a0, s0) + dot4(a1, s1);
    for (int m = 1; m < 64; m <<= 1) {
        saa += __shfl_xor(saa, m);
        sss += __shfl_xor(sss, m);
        sas += __shfl_xor(sas, m);
    }
    const float ra = rsqrtf(saa), rs = rsqrtf(sss);
    signed char* arow = aQ + (size_t)row * DIM;
    signed char* srow = sQ + (size_t)row * DIM;
    *(int*)(arow + lane * 4)       = q4(a0, ra * QS);
    *(int*)(arow + 256 + lane * 4) = q4(a1, ra * QS);
    *(int*)(srow + lane * 4)       = q4(s0, rs * QS);
    *(int*)(srow + 256 + lane * 4) = q4(s1, rs * QS);
    if (lane == 0) {
        diag[row] = sas * ra * rs * INV_T;
        // Uniform column weighting (incl. diagonal) is exact for the final
        // loss: only label==1 rows' lse is consumed, and those rows' diagonal
        // column has log_w==0 in the reference anyway. log2-weight: 0 or 1.
        lw2[row] = (labels[row] == 0) ? 1.0f : 0.0f;
    }
}

// ---------------------------------------------------------------------------
// Deterministic row compaction (prefix scan, no atomics -> bit-reproducible).
// perm[c] = c-th row with label==1; pad to 256-multiple with row 0 (their
// lsum slots are never consumed). meta[0]=npos, meta[1]=rtiles. Zeroes lsum.
// ---------------------------------------------------------------------------
__global__ __launch_bounds__(1024) void compact_kernel(
    const int* __restrict__ labels, int* __restrict__ perm,
    float* __restrict__ lsum, int* __restrict__ meta) {
    const int tid = threadIdx.x;
    for (int i = tid; i < 8448; i += 1024) {
        perm[i] = 0;
        lsum[i] = 0.f;
    }
    __syncthreads();
    const int lane = tid & 63, wid = tid >> 6;
    int lab[8], cnt = 0;
#pragma unroll
    for (int i = 0; i < 8; ++i) {
        lab[i] = labels[tid * 8 + i];
        cnt += (lab[i] == 1);
    }
    int inc = cnt;
    for (int d = 1; d < 64; d <<= 1) {
        int v = __shfl_up(inc, d);
        if (lane >= d) inc += v;
    }
    __shared__ int wsum[16], wpre[16];
    if (lane == 63) wsum[wid] = inc;
    __syncthreads();
    if (tid == 0) {
        int acc = 0;
        for (int w = 0; w < 16; ++w) { acc += wsum[w]; wpre[w] = acc; }
    }
    __syncthreads();
    int off = (wid ? wpre[wid - 1] : 0) + inc - cnt;  // exclusive prefix
#pragma unroll
    for (int i = 0; i < 8; ++i)
        if (lab[i] == 1) perm[off++] = tid * 8 + i;
    if (tid == 0) {
        meta[0] = wpre[15];
        meta[1] = (wpre[15] + 255) >> 8;  // active 256-row tiles
    }
}

// ---------------------------------------------------------------------------
// m201-template i8 GEMM + exp2 + row-sum over positive rows (v19).
// r15's template port failed for two now-identified reasons: i8@BK=64 gave
// half the template's per-phase MFMA thickness, and 3x32KB buffering
// deviated from the 2-deep full-size dbuf. Fixed: BK=128 (64 MFMA/K-tile,
// 16 MFMA = ~82 cyc per phase = template thickness) and 2 x 64 KB LDS
// (128 KB, 1 block/CU, 8 waves = m201's exact occupancy regime, 62% there).
// Block = 256 compact-rows x 256 cols, sweeping 2 cts -> 8 K-tiles; 4
// phases/K-tile {ds_read subtile + front-loaded staging -> bar -> lgkm0 ->
// sched_bar -> setprio 16 MFMA -> bar}; staging of tt+1 front-loaded into
// ph0 (A x4 rounds) / ph1 (B x4) so ph3's once-per-tile vmcnt(0) has
// ~2-3 phases of lead (cheap drain, 2-buf analog of counted vmcnt).
// Swizzle: r17-verified 8-slot involution (2-way banks at 128 B rows).
// Grid 512 (32 rt x 16 ctg), early-exit rt >= meta[1] (~272 active).
// ---------------------------------------------------------------------------
__global__ __launch_bounds__(512, 2) void lse_gemm(
    const signed char* __restrict__ Aq, const signed char* __restrict__ Bq,
    const float* __restrict__ lw2, const int* __restrict__ perm,
    const int* __restrict__ meta, float* __restrict__ lsum) {
    __shared__ __align__(16) char lds[131072];
    // buf stride 65536: A 32 KB @0 (256 rows x 128 B), B 32 KB @32768

    const int bid = blockIdx.x;  // 512 blocks
    const int rt = bid >> 4, ctg = bid & 15;
    if (rt >= meta[1]) return;  // inactive row-tile (input-deterministic)
    const int row0 = rt * 256;  // compact-row base
    const int colg = ctg * 512;

    const int tid = threadIdx.x;
    const int wid = tid >> 6, lane = tid & 63;
    const int wr = wid >> 2, wc = wid & 3;  // 2M x 4N; wave = 128 x 64
    const int fr = lane & 15, grp = lane >> 4;
    const int f7 = fr & 7;

    // staging: thread t -> row t>>3 of a 64-row round, phys slot t&7;
    // fetch logical slot (t&7)^((t>>3)&7)  [8-slot involution, r17-verified]
    const int sl = (tid & 7) ^ ((tid >> 3) & 7);
    // A row pointers (perm-gathered), one per round ra
    const signed char* aSrcs[4];
#pragma unroll
    for (int ra = 0; ra < 4; ++ra)
        aSrcs[ra] = Aq +
            (size_t)perm[row0 + ra * 64 + (tid >> 3)] * DIM + sl * 16;
    const signed char* bSrc =
        Bq + (size_t)(colg + (tid >> 3)) * DIM + sl * 16;
    char* dst = lds + tid * 16;

    // K-tile TT (0..7): ct = TT>>2, kt = TT&3 (byte offset kt*128).
#define STAGE_A4(buf, TT)                                                     \
    do {                                                                      \
        _Pragma("unroll")                                                     \
        for (int ra = 0; ra < 4; ++ra)                                        \
            gload_lds16(aSrcs[ra] + ((TT) & 3) * 128,                         \
                        dst + (buf) * 65536 + ra * 8192);                     \
    } while (0)
#define STAGE_B4(buf, TT)                                                     \
    do {                                                                      \
        _Pragma("unroll")                                                     \
        for (int rb = 0; rb < 4; ++rb)                                        \
            gload_lds16(bSrc + ((TT) >> 2) * 131072 + rb * 32768 +            \
                            ((TT) & 3) * 128,                                 \
                        dst + (buf) * 65536 + 32768 + rb * 8192);             \
    } while (0)

    // fragment reads: A row R = wr*128 + m*16 + fr at byte R*128 + psk;
    // B row = wc*64 + n*16 + fr at +32768. psk(ks) = ((ks*4+grp)^f7)*16.
    const char* rdA = lds + (wr * 128 + fr) * 128;
    const char* rdB = lds + 32768 + (wc * 64 + fr) * 128;
    const int psk0 = ((0 * 4 + grp) ^ f7) << 4;
    const int psk1 = ((1 * 4 + grp) ^ f7) << 4;

    // ---- prologue: tile 0 fully staged
    STAGE_A4(0, 0);
    STAGE_B4(0, 0);
    asm volatile("s_waitcnt vmcnt(0)" ::: "memory");
    block_bar();

    i32x4 a[4], b[4];
    i32x4 acc[8][4] = {};

#pragma unroll 1
    for (int tt = 0; tt < 8; ++tt) {
        const int buf = tt & 1, nbuf = buf ^ 1;
        const char* bA = rdA + buf * 65536;
        const char* bB = rdB + buf * 65536;

        // ---- ph0: a[m0-3,k0] + b[*,k0]; stage A(tt+1); MFMA Q(lo,k0)
#pragma unroll
        for (int m = 0; m < 4; ++m)
            a[m] = *(const i32x4*)(bA + m * 2048 + psk0);
#pragma unroll
        for (int n = 0; n < 4; ++n)
            b[n] = *(const i32x4*)(bB + n * 2048 + psk0);
        if (tt < 7) STAGE_A4(nbuf, tt + 1);
        block_bar();
        asm volatile("s_waitcnt lgkmcnt(0)" ::: "memory");
        __builtin_amdgcn_sched_barrier(0);
        __builtin_amdgcn_s_setprio(1);
#pragma unroll
        for (int m = 0; m < 4; ++m)
#pragma unroll
            for (int n = 0; n < 4; ++n)
                acc[m][n] = __builtin_amdgcn_mfma_i32_16x16x64_i8(
                    a[m], b[n], acc[m][n], 0, 0, 0);
        __builtin_amdgcn_s_setprio(0);
        block_bar();

        // ---- ph1: a[m4-7,k0]; stage B(tt+1); MFMA Q(hi,k0)
#pragma unroll
        for (int m = 0; m < 4; ++m)
            a[m] = *(const i32x4*)(bA + (m + 4) * 2048 + psk0);
        if (tt < 7) STAGE_B4(nbuf, tt + 1);
        block_bar();
        asm volatile("s_waitcnt lgkmcnt(0)" ::: "memory");
        __builtin_amdgcn_sched_barrier(0);
        __builtin_amdgcn_s_setprio(1);
#pragma unroll
        for (int m = 0; m < 4; ++m)
#pragma unroll
            for (int n = 0; n < 4; ++n)
                acc[m + 4][n] = __builtin_amdgcn_mfma_i32_16x16x64_i8(
                    a[m], b[n], acc[m + 4][n], 0, 0, 0);
        __builtin_amdgcn_s_setprio(0);
        block_bar();

        // ---- ph2: a[m0-3,k1] + b[*,k1]; MFMA Q(lo,k1)
#pragma unroll
        for (int m = 0; m < 4; ++m)
            a[m] = *(const i32x4*)(bA + m * 2048 + psk1);
#pragma unroll
        for (int n = 0; n < 4; ++n)
            b[n] = *(const i32x4*)(bB + n * 2048 + psk1);
        block_bar();
        asm volatile("s_waitcnt lgkmcnt(0)" ::: "memory");
        __builtin_amdgcn_sched_barrier(0);
        __builtin_amdgcn_s_setprio(1);
#pragma unroll
        for (int m = 0; m < 4; ++m)
#pragma unroll
            for (int n = 0; n < 4; ++n)
                acc[m][n] = __builtin_amdgcn_mfma_i32_16x16x64_i8(
                    a[m], b[n], acc[m][n], 0, 0, 0);
        __builtin_amdgcn_s_setprio(0);
        block_bar();

        // ---- ph3: a[m4-7,k1]; vmcnt(0) w/ 2-3 phase lead; MFMA Q(hi,k1)
#pragma unroll
        for (int m = 0; m < 4; ++m)
            a[m] = *(const i32x4*)(bA + (m + 4) * 2048 + psk1);
        asm volatile("s_waitcnt vmcnt(0)" ::: "memory");  // tt+1 staged
        block_bar();
        asm volatile("s_waitcnt lgkmcnt(0)" ::: "memory");
        __builtin_amdgcn_sched_barrier(0);
        __builtin_amdgcn_s_setprio(1);
#pragma unroll
        for (int m = 0; m < 4; ++m)
#pragma unroll
            for (int n = 0; n < 4; ++n)
                acc[m + 4][n] = __builtin_amdgcn_mfma_i32_16x16x64_i8(
                    a[m], b[n], acc[m + 4][n], 0, 0, 0);
        __builtin_amdgcn_s_setprio(0);
        block_bar();

        if ((tt & 3) == 3) {
            // per-ct epilogue (register-lean, in-cage): dequant -> exp2 ->
            // 16-lane reduce -> atomicAdd into compact lsum; re-zero acc.
            const int ct = tt >> 2;
            const int col0 = colg + ct * 256 + wc * 64;
            float lwv[4];
#pragma unroll
            for (int n = 0; n < 4; ++n)
                lwv[n] = lw2[col0 + n * 16 + fr];
#pragma unroll
            for (int m = 0; m < 8; ++m)
#pragma unroll
                for (int j = 0; j < 4; ++j) {
                    float s = 0.f;
#pragma unroll
                    for (int n = 0; n < 4; ++n)
                        s += hw_exp2(fmaf((float)acc[m][n][j], DEQ2, lwv[n]));
                    s += __shfl_xor(s, 1);
                    s += __shfl_xor(s, 2);
                    s += __shfl_xor(s, 4);
                    s += __shfl_xor(s, 8);
                    if (fr == 0)
                        atomicAdd(&lsum[row0 + wr * 128 + m * 16 + grp * 4 + j], s);
                }
#pragma unroll
            for (int m = 0; m < 8; ++m)
#pragma unroll
                for (int n = 0; n < 4; ++n)
                    acc[m][n] = i32x4{0, 0, 0, 0};
        }
    }
#undef STAGE_A4
#undef STAGE_B4
}

// 1024 threads, single block: final scalar reduction.
// Positive terms via perm gather; negative max over original diag.
__global__ __launch_bounds__(1024) void finalize_kernel(
    const float* __restrict__ lsum, const float* __restrict__ diag,
    const int* __restrict__ labels, const int* __restrict__ perm,
    const int* __restrict__ meta, float* __restrict__ out) {
    const int tid = threadIdx.x;
    const int npos = meta[0];
    float sl = 0.f, sd = 0.f, mx = -1e9f;
    int nn_ = 0;
    for (int c = tid; c < npos; c += 1024) {
        const int r = perm[c];
        const float dg = diag[r];
        sl += logf(lsum[c]) - dg;
        sd += dg;
    }
    for (int i = tid; i < NROWS; i += 1024) {
        if (labels[i] == 0) {
            nn_++;
            mx = fmaxf(mx, diag[i]);
        }
    }
    for (int m = 1; m < 64; m <<= 1) {
        sl += __shfl_xor(sl, m);
        sd += __shfl_xor(sd, m);
        mx = fmaxf(mx, __shfl_xor(mx, m));
        nn_ += __shfl_xor(nn_, m);
    }
    __shared__ float rsl[16], rsd[16], rmx[16];
    __shared__ int rnn[16];
    const int wave = tid >> 6, lane = tid & 63;
    if (lane == 0) {
        rsl[wave] = sl; rsd[wave] = sd; rmx[wave] = mx; rnn[wave] = nn_;
    }
    __syncthreads();
    if (tid == 0) {
        float SL = 0.f, SD = 0.f, MX = -1e9f;
        int NN = 0;
        for (int w = 0; w < 16; w++) {
            SL += rsl[w]; SD += rsd[w]; MX = fmaxf(MX, rmx[w]); NN += rnn[w];
        }
        const float infonce = SL / (float)npos;
        const float meanpos = SD / (float)npos;
        float pen = fmaxf(MX - meanpos + 0.2f, 0.0f);
        if (NN == 0) pen = 0.0f;
        out[0] = infonce + pen;
    }
}

extern "C" void kernel_launch(void* const* d_in, const int* in_sizes, int n_in,
                              void* d_out, int out_size, void* d_ws, size_t ws_size,
                              hipStream_t stream) {
    const float* A = (const float*)d_in[0];
    const float* S = (const float*)d_in[1];
    const int* labels = (const int*)d_in[2];
    float* out = (float*)d_out;

    char* ws = (char*)d_ws;
    signed char* aQ = (signed char*)ws;                          // 4 MB
    signed char* sQ = (signed char*)(ws + (size_t)NROWS * DIM);  // 4 MB
    char* p = ws + (size_t)NROWS * DIM * 2;
    float* diag = (float*)p;                   // 32 KB
    float* lw2 = (float*)(p + 32768);          // 32 KB
    float* lsum = (float*)(p + 65536);         // 8448 floats (36 KB slot)
    int* perm = (int*)(p + 65536 + 36864);     // 8448 ints (36 KB slot)
    int* meta = (int*)(p + 65536 + 73728);     // 2 ints

    norm_kernel<<<NROWS / 4, 256, 0, stream>>>(A, S, labels, aQ, sQ, diag, lw2);
    compact_kernel<<<1, 1024, 0, stream>>>(labels, perm, lsum, meta);
    lse_gemm<<<512, 512, 0, stream>>>(aQ, sQ, lw2, perm, meta, lsum);
    finalize_kernel<<<1, 1024, 0, stream>>>(lsum, diag, labels, perm, meta, out);
}

// Round 20
// 56.806 us; speedup vs baseline: 1.0396x; 1.0396x over previous
//
#include <hip/hip_runtime.h>
#include <math.h>

#define NROWS 8192
#define DIM 512
#define INV_T 20.0f
#define QS 500.0f
// dequant * 1/T * log2(e), for exp2-based softmax accumulation
#define DEQ2 (INV_T * 1.4426950408889634f / (QS * QS))

typedef __attribute__((ext_vector_type(4))) int i32x4;

__device__ __forceinline__ void gload_lds16(const void* g, void* l) {
    __builtin_amdgcn_global_load_lds(
        (const __attribute__((address_space(1))) unsigned int*)g,
        (__attribute__((address_space(3))) unsigned int*)l, 16, 0, 0);
}

__device__ __forceinline__ void block_bar() {
    asm volatile("" ::: "memory");
    __builtin_amdgcn_s_barrier();
    asm volatile("" ::: "memory");
}

__device__ __forceinline__ float hw_exp2(float x) {
    float r;
    asm("v_exp_f32 %0, %1" : "=v"(r) : "v"(x));  // D = 2^S0, 1 inst
    return r;
}

__device__ __forceinline__ float dot4(float4 a, float4 b) {
    return a.x * b.x + a.y * b.y + a.z * b.z + a.w * b.w;
}

__device__ __forceinline__ int q4(float4 v, float s) {
    int b0 = __float2int_rn(fminf(fmaxf(v.x * s, -127.f), 127.f)) & 255;
    int b1 = __float2int_rn(fminf(fmaxf(v.y * s, -127.f), 127.f)) & 255;
    int b2 = __float2int_rn(fminf(fmaxf(v.z * s, -127.f), 127.f)) & 255;
    int b3 = __float2int_rn(fminf(fmaxf(v.w * s, -127.f), 127.f)) & 255;
    return b0 | (b1 << 8) | (b2 << 16) | (b3 << 24);
}

// One wave per row: L2-normalize, quantize to i8 (scale QS), exact fp32 diag,
// column log2-weights (0 or 1).
__global__ __launch_bounds__(256) void norm_kernel(
    const float* __restrict__ A, const float* __restrict__ S,
    const int* __restrict__ labels, signed char* __restrict__ aQ,
    signed char* __restrict__ sQ, float* __restrict__ diag,
    float* __restrict__ lw2) {
    const int wave = threadIdx.x >> 6, lane = threadIdx.x & 63;
    const int row = blockIdx.x * 4 + wave;
    const float4* a4 = (const float4*)(A + (size_t)row * DIM);
    const float4* s4 = (const float4*)(S + (size_t)row * DIM);
    float4 a0 = a4[lane], a1 = a4[lane + 64];
    float4 s0 = s4[lane], s1 = s4[lane + 64];
    float saa = dot4(a0, a0) + dot4(a1, a1);
    float sss = dot4(s0, s0) + dot4(s1, s1);
    float sas = dot4(a0, s0) + dot4(a1, s1);
    for (int m = 1; m < 64; m <<= 1) {
        saa += __shfl_xor(saa, m);
        sss += __shfl_xor(sss, m);
        sas += __shfl_xor(sas, m);
    }
    const float ra = rsqrtf(saa), rs = rsqrtf(sss);
    signed char* arow = aQ + (size_t)row * DIM;
    signed char* srow = sQ + (size_t)row * DIM;
    *(int*)(arow + lane * 4)       = q4(a0, ra * QS);
    *(int*)(arow + 256 + lane * 4) = q4(a1, ra * QS);
    *(int*)(srow + lane * 4)       = q4(s0, rs * QS);
    *(int*)(srow + 256 + lane * 4) = q4(s1, rs * QS);
    if (lane == 0) {
        diag[row] = sas * ra * rs * INV_T;
        // Uniform column weighting (incl. diagonal) is exact for the final
        // loss: only label==1 rows' lse is consumed, and those rows' diagonal
        // column has log_w==0 in the reference anyway. log2-weight: 0 or 1.
        lw2[row] = (labels[row] == 0) ? 1.0f : 0.0f;
    }
}

// ---------------------------------------------------------------------------
// Deterministic row compaction (prefix scan, no atomics -> bit-reproducible).
// perm[c] = c-th row with label==1; pad to 256-multiple with row 0 (their
// lsum slots are never consumed). meta[0]=npos, meta[1]=rtiles. Zeroes lsum.
// ---------------------------------------------------------------------------
__global__ __launch_bounds__(1024) void compact_kernel(
    const int* __restrict__ labels, int* __restrict__ perm,
    float* __restrict__ lsum, int* __restrict__ meta) {
    const int tid = threadIdx.x;
    for (int i = tid; i < 8448; i += 1024) {
        perm[i] = 0;
        lsum[i] = 0.f;
    }
    __syncthreads();
    const int lane = tid & 63, wid = tid >> 6;
    int lab[8], cnt = 0;
#pragma unroll
    for (int i = 0; i < 8; ++i) {
        lab[i] = labels[tid * 8 + i];
        cnt += (lab[i] == 1);
    }
    int inc = cnt;
    for (int d = 1; d < 64; d <<= 1) {
        int v = __shfl_up(inc, d);
        if (lane >= d) inc += v;
    }
    __shared__ int wsum[16], wpre[16];
    if (lane == 63) wsum[wid] = inc;
    __syncthreads();
    if (tid == 0) {
        int acc = 0;
        for (int w = 0; w < 16; ++w) { acc += wsum[w]; wpre[w] = acc; }
    }
    __syncthreads();
    int off = (wid ? wpre[wid - 1] : 0) + inc - cnt;  // exclusive prefix
#pragma unroll
    for (int i = 0; i < 8; ++i)
        if (lab[i] == 1) perm[off++] = tid * 8 + i;
    if (tid == 0) {
        meta[0] = wpre[15];
        meta[1] = (wpre[15] + 255) >> 8;  // active 256-row tiles
    }
}

// ---------------------------------------------------------------------------
// Phased i8 GEMM + exp2 + row-sum over POSITIVE ROWS ONLY (r18 chassis,
// restored after r19's template regression). Reference consumes lse only
// where label==1 (~N/2): negative rows need only their diag. ~2x FLOP cut.
// Grid fixed at 512 (graph-safe); rt = bid>>4, ctg = bid&15; blocks with
// rt >= meta.rtiles exit immediately. Chassis = r12 (proven): 512 thr =
// 8 waves (4x2), tile 256 compact-rows x 512 cols (4-ct sweep), 48 KB LDS
// dbuf, vmcnt(3), verified 4-slot involution swizzles, register-lean
// in-cage epilogue, 2 blocks/CU.
// ---------------------------------------------------------------------------
__global__ __launch_bounds__(512, 4) void lse_gemm(
    const signed char* __restrict__ Aq, const signed char* __restrict__ Bq,
    const float* __restrict__ lw2, const int* __restrict__ perm,
    const int* __restrict__ meta, float* __restrict__ lsum) {
    __shared__ __align__(16) char lds[49152];
    // buf layout (stride 24576): A 16 KB @0, B 8 KB @16384

    const int bid = blockIdx.x;  // 512 blocks
    const int rt = bid >> 4, ctg = bid & 15;
    if (rt >= meta[1]) return;  // inactive row-tile (input-deterministic)
    const int row0 = rt * 256;  // compact-row base
    const int colg = ctg * 512;

    const int tid = threadIdx.x;
    const int wid = tid >> 6, lane = tid & 63;
    const int wr = wid >> 1, wc = wid & 1;  // 4x2 wave grid (64x64 each)
    const int fr = lane & 15, grp = lane >> 4;

    // staging: thread t -> compact row t>>2 (+128 second half), phys slot
    // t&3; fetch logical slot (t&3)^((t>>3)&3) [4-slot involution, verified;
    // swizzle lives in the k-slot dim -> unaffected by row gather].
    const int sl = (tid & 3) ^ ((tid >> 3) & 3);
    const int r0 = perm[row0 + (tid >> 2)];
    const int r1 = perm[row0 + 128 + (tid >> 2)];
    const signed char* aSrc0 = Aq + (size_t)r0 * DIM + sl * 16;
    const signed char* aSrc1 = Aq + (size_t)r1 * DIM + sl * 16;
    const signed char* bSrc = Bq + (size_t)(colg + (tid >> 2)) * DIM + sl * 16;
    char* dstA = lds + tid * 16;          // + buf*24576 (+8192 rows 128+)
    char* dstB = lds + 16384 + tid * 16;  // + buf*24576

    // K-step TT (0..31): ct = TT>>3, k = TT&7. 3 loads per thread per step.
#define STAGE(buf, TT)                                                        \
    do {                                                                      \
        const int ct_ = (TT) >> 3, k_ = (TT) & 7;                             \
        gload_lds16(aSrc0 + k_ * 64,              dstA + (buf) * 24576);      \
        gload_lds16(aSrc1 + k_ * 64,              dstA + (buf) * 24576 + 8192); \
        gload_lds16(bSrc + ct_ * 65536 + k_ * 64, dstB + (buf) * 24576);      \
    } while (0)

    // fragment reads: A row R = wr*64 + m*16 + fr at byte R*64 + ps;
    // B row = wc*64 + n*16 + fr. ps = (grp ^ ((fr>>1)&3))*16.
    const int ps = (grp ^ ((fr >> 1) & 3)) << 4;
    const char* rdA = lds + (wr * 64 + fr) * 64 + ps;
    const char* rdB = lds + 16384 + (wc * 64 + fr) * 64 + ps;

    STAGE(0, 0);

    i32x4 acc[4][4] = {};
#pragma unroll 2
    for (int T = 0; T < 32; ++T) {
        const int buf = T & 1;
        if (T < 31) {
            STAGE(buf ^ 1, T + 1);
            asm volatile("s_waitcnt vmcnt(3)" ::: "memory");
        } else {
            asm volatile("s_waitcnt vmcnt(0)" ::: "memory");
        }
        block_bar();  // buf(T) staged by all waves

        i32x4 a[4], b[4];
#pragma unroll
        for (int m = 0; m < 4; ++m)
            a[m] = *(const i32x4*)(rdA + buf * 24576 + m * 1024);
#pragma unroll
        for (int n = 0; n < 4; ++n)
            b[n] = *(const i32x4*)(rdB + buf * 24576 + n * 1024);
        asm volatile("s_waitcnt lgkmcnt(0)" ::: "memory");
        __builtin_amdgcn_sched_barrier(0);  // rule 18: pin MFMA after lgkm

        __builtin_amdgcn_s_setprio(1);
#pragma unroll
        for (int m = 0; m < 4; ++m)
#pragma unroll
            for (int n = 0; n < 4; ++n)
                acc[m][n] = __builtin_amdgcn_mfma_i32_16x16x64_i8(
                    a[m], b[n], acc[m][n], 0, 0, 0);
        __builtin_amdgcn_s_setprio(0);

        if ((T & 7) == 7) {
            // register-lean in-cage epilogue (r10/r12-proven): dequant ->
            // exp2 -> 16-lane reduce -> atomicAdd into compact lsum slot.
            const int ct = T >> 3;
            const int col0 = colg + ct * 128 + wc * 64;
            float lwv[4];
#pragma unroll
            for (int n = 0; n < 4; ++n)
                lwv[n] = lw2[col0 + n * 16 + fr];
#pragma unroll
            for (int m = 0; m < 4; ++m)
#pragma unroll
                for (int j = 0; j < 4; ++j) {
                    float s = 0.f;
#pragma unroll
                    for (int n = 0; n < 4; ++n)
                        s += hw_exp2(fmaf((float)acc[m][n][j], DEQ2, lwv[n]));
                    s += __shfl_xor(s, 1);
                    s += __shfl_xor(s, 2);
                    s += __shfl_xor(s, 4);
                    s += __shfl_xor(s, 8);
                    if (fr == 0)
                        atomicAdd(&lsum[row0 + wr * 64 + m * 16 + grp * 4 + j], s);
                }
#pragma unroll
            for (int m = 0; m < 4; ++m)
#pragma unroll
                for (int n = 0; n < 4; ++n)
                    acc[m][n] = i32x4{0, 0, 0, 0};
        }
        block_bar();  // buf(T) reads done before overwrite
    }
#undef STAGE
}

// 1024 threads, single block: final scalar reduction.
// Positive terms via perm gather; negative max over original diag.
__global__ __launch_bounds__(1024) void finalize_kernel(
    const float* __restrict__ lsum, const float* __restrict__ diag,
    const int* __restrict__ labels, const int* __restrict__ perm,
    const int* __restrict__ meta, float* __restrict__ out) {
    const int tid = threadIdx.x;
    const int npos = meta[0];
    float sl = 0.f, sd = 0.f, mx = -1e9f;
    int nn_ = 0;
    for (int c = tid; c < npos; c += 1024) {
        const int r = perm[c];
        const float dg = diag[r];
        sl += logf(lsum[c]) - dg;
        sd += dg;
    }
    for (int i = tid; i < NROWS; i += 1024) {
        if (labels[i] == 0) {
            nn_++;
            mx = fmaxf(mx, diag[i]);
        }
    }
    for (int m = 1; m < 64; m <<= 1) {
        sl += __shfl_xor(sl, m);
        sd += __shfl_xor(sd, m);
        mx = fmaxf(mx, __shfl_xor(mx, m));
        nn_ += __shfl_xor(nn_, m);
    }
    __shared__ float rsl[16], rsd[16], rmx[16];
    __shared__ int rnn[16];
    const int wave = tid >> 6, lane = tid & 63;
    if (lane == 0) {
        rsl[wave] = sl; rsd[wave] = sd; rmx[wave] = mx; rnn[wave] = nn_;
    }
    __syncthreads();
    if (tid == 0) {
        float SL = 0.f, SD = 0.f, MX = -1e9f;
        int NN = 0;
        for (int w = 0; w < 16; w++) {
            SL += rsl[w]; SD += rsd[w]; MX = fmaxf(MX, rmx[w]); NN += rnn[w];
        }
        const float infonce = SL / (float)npos;
        const float meanpos = SD / (float)npos;
        float pen = fmaxf(MX - meanpos + 0.2f, 0.0f);
        if (NN == 0) pen = 0.0f;
        out[0] = infonce + pen;
    }
}

extern "C" void kernel_launch(void* const* d_in, const int* in_sizes, int n_in,
                              void* d_out, int out_size, void* d_ws, size_t ws_size,
                              hipStream_t stream) {
    const float* A = (const float*)d_in[0];
    const float* S = (const float*)d_in[1];
    const int* labels = (const int*)d_in[2];
    float* out = (float*)d_out;

    char* ws = (char*)d_ws;
    signed char* aQ = (signed char*)ws;                          // 4 MB
    signed char* sQ = (signed char*)(ws + (size_t)NROWS * DIM);  // 4 MB
    char* p = ws + (size_t)NROWS * DIM * 2;
    float* diag = (float*)p;                   // 32 KB
    float* lw2 = (float*)(p + 32768);          // 32 KB
    float* lsum = (float*)(p + 65536);         // 8448 floats (36 KB slot)
    int* perm = (int*)(p + 65536 + 36864);     // 8448 ints (36 KB slot)
    int* meta = (int*)(p + 65536 + 73728);     // 2 ints

    norm_kernel<<<NROWS / 4, 256, 0, stream>>>(A, S, labels, aQ, sQ, diag, lw2);
    compact_kernel<<<1, 1024, 0, stream>>>(labels, perm, lsum, meta);
    lse_gemm<<<512, 512, 0, stream>>>(aQ, sQ, lw2, perm, meta, lsum);
    finalize_kernel<<<1, 1024, 0, stream>>>(lsum, diag, labels, perm, meta, out);
}